// Round 10
// baseline (46.091 us; speedup 1.0000x reference)
//
#include <hip/hip_runtime.h>

// Grapher block (DeepGCN MRConv) on MI355X — bf16 MFMA, 2-kernel, on-the-fly
// weight conversion (no prep kernel).
// fc1 (coalesced+XOR-swizzled LDS transpose of x) -> fused mr+fc2.
// Scratch (d_ws): xn bf16 [32768][128] (8MB).
//
// MFMA 16x16x32 bf16 layout (guide §3, m89-verified):
//   A: row = lane&15, k = (lane>>4)*8 + j   (bf16x8 contiguous in k)
//   B: col = lane&15, k = (lane>>4)*8 + j
//   D: col = lane&15, row = (lane>>4)*4 + r
//
// NOTE (rounds 7-9): cooperative fc1+mr fusion raced — cross-XCD L2 dirty
// lines of xn are NOT made visible by agent-scope __threadfence on gfx950;
// kernel boundary is the reliable publish point. Keep 2 kernels.

typedef short bf8_t __attribute__((ext_vector_type(8)));
typedef float f4_t  __attribute__((ext_vector_type(4)));

namespace {
constexpr int Bn = 8, Cc = 128, Nn = 4096, Kk = 16, C2 = 256;
constexpr int NODES = Bn * Nn;
constexpr float EPSf = 1e-5f;
}

__device__ __forceinline__ unsigned short f2bf(float f) {
    unsigned u = __float_as_uint(f);
    u += 0x7fffu + ((u >> 16) & 1u);   // RNE
    return (unsigned short)(u >> 16);
}
__device__ __forceinline__ unsigned pk2(float a, float b) {
    return (unsigned)f2bf(a) | ((unsigned)f2bf(b) << 16);
}
__device__ __forceinline__ float bflo(unsigned u) { return __uint_as_float(u << 16); }
__device__ __forceinline__ float bfhi(unsigned u) { return __uint_as_float(u & 0xffff0000u); }
__device__ __forceinline__ unsigned diff2(unsigned o, unsigned m) {
    return pk2(bflo(o) - bflo(m), bfhi(o) - bfhi(m));
}

// load 8 consecutive fp32 weights and convert to one bf16x8 MFMA fragment
__device__ __forceinline__ bf8_t cvt_frag(const float* __restrict__ p) {
    const float4 a = *(const float4*)(p);
    const float4 b = *(const float4*)(p + 4);
    union { uint4 u; bf8_t f; } r;
    r.u.x = pk2(a.x, a.y);
    r.u.y = pk2(a.z, a.w);
    r.u.z = pk2(b.x, b.y);
    r.u.w = pk2(b.z, b.w);
    return r.f;
}

// packed u16 min: valid as bf16-min because all values are >= 0 (post-ReLU)
#define PKMIN(a, b) asm("v_pk_min_u16 %0, %0, %1" : "+v"(a) : "v"(b))

// ---------------------------------------------------------------------------
// fc1: xn[n][o] = relu( BN( sum_c W1[o][c]*x[b][c][n] ) )
// block: 512 thr = 8 waves, tile 64 nodes x 128 o; wave w -> o-band 16w.
// A = W1 rows (fp32->bf16 on the fly); B = x^T from XOR-swizzled LDS;
// D row=o -> packed uint2 stores. lb swizzle matches mrfc2 (perf hint).
// ---------------------------------------------------------------------------
__global__ __launch_bounds__(512) void fc1_mfma(
    const float* __restrict__ x, const float* __restrict__ W1,
    const float* __restrict__ b1, const float* __restrict__ g1,
    const float* __restrict__ be1, const float* __restrict__ m1,
    const float* __restrict__ v1, ushort* __restrict__ xn)
{
    __shared__ __align__(16) ushort xS[64 * 136];   // 17.4 KB
    __shared__ float scS[Cc], shS[Cc];
    const int t = threadIdx.x;
    const int bid = blockIdx.x;
    const int lb = (bid & 7) * 64 + (bid >> 3);     // XCD-local batch mapping
    const int node0 = lb * 64;
    const int b  = node0 >> 12;
    const int n0 = node0 & 4095;

    if (t < Cc) {
        const float s = g1[t] * rsqrtf(v1[t] + EPSf);
        scS[t] = s;
        shS[t] = (b1[t] - m1[t]) * s + be1[t];
    }

    // stage: thread = channels (2cp, 2cp+1) x 8 consecutive n (coalesced)
    {
        const int cp = t >> 3, q = t & 7;            // n = q*8 .. q*8+7
        const float* p0 = x + ((size_t)(b * Cc + 2 * cp)) * Nn + n0 + q * 8;
        const float* p1 = p0 + Nn;
        const float4 a0 = *(const float4*)(p0);
        const float4 a1 = *(const float4*)(p0 + 4);
        const float4 c0 = *(const float4*)(p1);
        const float4 c1 = *(const float4*)(p1 + 4);
        ushort* base = xS + (size_t)q * 8 * 136 + ((cp * 2) ^ (q << 3));
        *(unsigned*)(base + 0 * 136) = pk2(a0.x, c0.x);
        *(unsigned*)(base + 1 * 136) = pk2(a0.y, c0.y);
        *(unsigned*)(base + 2 * 136) = pk2(a0.z, c0.z);
        *(unsigned*)(base + 3 * 136) = pk2(a0.w, c0.w);
        *(unsigned*)(base + 4 * 136) = pk2(a1.x, c1.x);
        *(unsigned*)(base + 5 * 136) = pk2(a1.y, c1.y);
        *(unsigned*)(base + 6 * 136) = pk2(a1.z, c1.z);
        *(unsigned*)(base + 7 * 136) = pk2(a1.w, c1.w);
    }
    __syncthreads();

    const int w = t >> 6, lane = t & 63;
    const int row16 = lane & 15, kg = lane >> 4;

    f4_t acc[4];  // [nsub]
    const f4_t zero = {0.f, 0.f, 0.f, 0.f};
    #pragma unroll
    for (int j = 0; j < 4; ++j) acc[j] = zero;

    #pragma unroll
    for (int ks = 0; ks < 4; ++ks) {
        const int k0 = ks * 32 + kg * 8;
        const bf8_t aw = cvt_frag(W1 + (size_t)(w * 16 + row16) * Cc + k0);
        #pragma unroll
        for (int nsub = 0; nsub < 4; ++nsub) {
            const int n = nsub * 16 + row16;
            const bf8_t bx = *(const bf8_t*)(xS + n * 136 + (k0 ^ ((n >> 3) << 3)));
            acc[nsub] = __builtin_amdgcn_mfma_f32_16x16x32_bf16(aw, bx, acc[nsub], 0, 0, 0);
        }
    }

    // epilogue: lane owns o = o4..o4+3 (consecutive) for 4 node rows -> uint2
    const int o4 = w * 16 + kg * 4;
    const float s0 = scS[o4 + 0], s1 = scS[o4 + 1], s2 = scS[o4 + 2], s3 = scS[o4 + 3];
    const float h0 = shS[o4 + 0], h1 = shS[o4 + 1], h2 = shS[o4 + 2], h3 = shS[o4 + 3];
    #pragma unroll
    for (int nsub = 0; nsub < 4; ++nsub) {
        const int node = node0 + nsub * 16 + row16;
        float v0 = acc[nsub][0] * s0 + h0;
        float v1 = acc[nsub][1] * s1 + h1;
        float v2 = acc[nsub][2] * s2 + h2;
        float v3 = acc[nsub][3] * s3 + h3;
        v0 = v0 > 0.f ? v0 : 0.f;
        v1 = v1 > 0.f ? v1 : 0.f;
        v2 = v2 > 0.f ? v2 : 0.f;
        v3 = v3 > 0.f ? v3 : 0.f;
        uint2 pk;
        pk.x = pk2(v0, v1);
        pk.y = pk2(v2, v3);
        *(uint2*)(xn + (size_t)node * Cc + o4) = pk;
    }
}

// ---------------------------------------------------------------------------
// fused mr+fc2 per 64-node tile, 512 thr = 8 waves:
//   P1: cat = [xn | xn - min_k xn[src]]  -> catS (8 thr/node, 16-ch slices)
//   P2: hn  = relu(Wmr @ cat^T + bmr)    wave j-band 32; packed writeback->catS
//   P3: out = relu( BN(W2 @ hn^T) + x )  wave o-band 16
// Wmr/W2 fragments converted fp32->bf16 on the fly (L2-resident weights).
// XCD swizzle: bid%8 -> batch, so gathers hit XCD-local L2.
// ---------------------------------------------------------------------------
__global__ __launch_bounds__(512) void mrfc2_mfma(
    const ushort* __restrict__ xn, const int* __restrict__ src,
    const float* __restrict__ Wmr, const float* __restrict__ bmr,
    const float* __restrict__ W2, const float* __restrict__ x,
    const float* __restrict__ b2, const float* __restrict__ g2,
    const float* __restrict__ be2, const float* __restrict__ m2,
    const float* __restrict__ v2, float* __restrict__ out)
{
    __shared__ __align__(16) ushort catS[64 * 264];  // [node][256] pad->264
    __shared__ int srcS[64 * Kk];
    __shared__ float scS[Cc], shS[Cc];
    const int t = threadIdx.x;
    const int bid = blockIdx.x;
    const int lb = (bid & 7) * 64 + (bid >> 3);      // XCD-local batch mapping
    const int node0 = lb * 64;
    const int b  = node0 >> 12;
    const int n0 = node0 & 4095;

    if (t < Cc) {
        const float s = g2[t] * rsqrtf(v2[t] + EPSf);
        scS[t] = s;
        shS[t] = (b2[t] - m2[t]) * s + be2[t];
    }
    if (t < 256)
        ((int4*)srcS)[t] = ((const int4*)(src + (size_t)node0 * Kk))[t];
    __syncthreads();

    {   // P1: gather + u16-min + diff; 8 threads/node, 16 channels each
        const int nl = t >> 3, q = t & 7;
        const ushort* orow = xn + (size_t)(node0 + nl) * Cc + q * 16;
        uint4 ow0 = *(const uint4*)(orow + 0);
        uint4 ow1 = *(const uint4*)(orow + 8);
        const int* sl = srcS + nl * Kk;
        const ushort* sr = xn + (size_t)sl[0] * Cc + q * 16;
        uint4 mn0 = *(const uint4*)(sr + 0);
        uint4 mn1 = *(const uint4*)(sr + 8);
        #pragma unroll
        for (int k = 1; k < Kk; ++k) {
            const ushort* s = xn + (size_t)sl[k] * Cc + q * 16;
            uint4 v0 = *(const uint4*)(s + 0);
            uint4 v1 = *(const uint4*)(s + 8);
            PKMIN(mn0.x, v0.x); PKMIN(mn0.y, v0.y); PKMIN(mn0.z, v0.z); PKMIN(mn0.w, v0.w);
            PKMIN(mn1.x, v1.x); PKMIN(mn1.y, v1.y); PKMIN(mn1.z, v1.z); PKMIN(mn1.w, v1.w);
        }
        unsigned* crow = (unsigned*)(catS + nl * 264);
        *(uint4*)(crow + q * 8 + 0) = ow0;
        *(uint4*)(crow + q * 8 + 4) = ow1;
        uint4 d0, d1;
        d0.x = diff2(ow0.x, mn0.x); d0.y = diff2(ow0.y, mn0.y);
        d0.z = diff2(ow0.z, mn0.z); d0.w = diff2(ow0.w, mn0.w);
        d1.x = diff2(ow1.x, mn1.x); d1.y = diff2(ow1.y, mn1.y);
        d1.z = diff2(ow1.z, mn1.z); d1.w = diff2(ow1.w, mn1.w);
        *(uint4*)(crow + 64 + q * 8 + 0) = d0;
        *(uint4*)(crow + 64 + q * 8 + 4) = d1;
    }
    __syncthreads();

    const int w = t >> 6, lane = t & 63;
    const int row16 = lane & 15, kg = lane >> 4;

    // ---- P2: hn j-band = relu(Wmr[jb:jb+32] @ cat^T + bmr)  (D: row=j)
    const int jb = w * 32;
    {
        f4_t acc[2][4];  // [jsub][nsub]
        const f4_t zero = {0.f, 0.f, 0.f, 0.f};
        #pragma unroll
        for (int i = 0; i < 2; ++i)
            #pragma unroll
            for (int j = 0; j < 4; ++j) acc[i][j] = zero;

        #pragma unroll
        for (int ks = 0; ks < 8; ++ks) {
            const int k0 = ks * 32 + kg * 8;
            bf8_t aw[2], bc[4];
            #pragma unroll
            for (int jsub = 0; jsub < 2; ++jsub)
                aw[jsub] = cvt_frag(Wmr + (size_t)(jb + jsub * 16 + row16) * C2 + k0);
            #pragma unroll
            for (int nsub = 0; nsub < 4; ++nsub)
                bc[nsub] = *(const bf8_t*)(catS + (nsub * 16 + row16) * 264 + k0);
            #pragma unroll
            for (int jsub = 0; jsub < 2; ++jsub)
                #pragma unroll
                for (int nsub = 0; nsub < 4; ++nsub)
                    acc[jsub][nsub] = __builtin_amdgcn_mfma_f32_16x16x32_bf16(
                        aw[jsub], bc[nsub], acc[jsub][nsub], 0, 0, 0);
        }
        __syncthreads();  // all P2 reads of catS complete

        // writeback hn into catS: lane's 4 acc rows are consecutive j -> uint2
        #pragma unroll
        for (int jsub = 0; jsub < 2; ++jsub) {
            const float4 bb = *(const float4*)(bmr + jb + jsub * 16 + kg * 4);
            #pragma unroll
            for (int nsub = 0; nsub < 4; ++nsub) {
                float v0 = acc[jsub][nsub][0] + bb.x;
                float v1 = acc[jsub][nsub][1] + bb.y;
                float v2_ = acc[jsub][nsub][2] + bb.z;
                float v3 = acc[jsub][nsub][3] + bb.w;
                v0 = v0 > 0.f ? v0 : 0.f;
                v1 = v1 > 0.f ? v1 : 0.f;
                v2_ = v2_ > 0.f ? v2_ : 0.f;
                v3 = v3 > 0.f ? v3 : 0.f;
                uint2 pk;
                pk.x = pk2(v0, v1);
                pk.y = pk2(v2_, v3);
                *(uint2*)(catS + (nsub * 16 + row16) * 264 + jb + jsub * 16 + kg * 4) = pk;
            }
        }
    }
    __syncthreads();

    // ---- P3: out o-band = relu(BN2(W2[ob:ob+16] @ hn^T) + x)  (D: row=o)
    {
        const int ob = w * 16;
        f4_t acc[4];  // [nsub]
        const f4_t zero = {0.f, 0.f, 0.f, 0.f};
        #pragma unroll
        for (int j = 0; j < 4; ++j) acc[j] = zero;

        #pragma unroll
        for (int ks = 0; ks < 8; ++ks) {
            const int k0 = ks * 32 + kg * 8;
            const bf8_t aw = cvt_frag(W2 + (size_t)(ob + row16) * C2 + k0);
            #pragma unroll
            for (int nsub = 0; nsub < 4; ++nsub) {
                const bf8_t bh = *(const bf8_t*)(catS + (nsub * 16 + row16) * 264 + k0);
                acc[nsub] = __builtin_amdgcn_mfma_f32_16x16x32_bf16(aw, bh, acc[nsub], 0, 0, 0);
            }
        }

        #pragma unroll
        for (int r = 0; r < 4; ++r) {
            const int o = ob + kg * 4 + r;
            const float s = scS[o], sh = shS[o];
            const float* xr = x   + ((size_t)(b * Cc + o)) * Nn + n0;
            float*       op = out + ((size_t)(b * Cc + o)) * Nn + n0;
            #pragma unroll
            for (int nsub = 0; nsub < 4; ++nsub) {
                const int nn = nsub * 16 + row16;
                float v = acc[nsub][r] * s + sh + xr[nn];
                v = v > 0.f ? v : 0.f;
                op[nn] = v;
            }
        }
    }
}

// ---------------------------------------------------------------------------
extern "C" void kernel_launch(void* const* d_in, const int* in_sizes, int n_in,
                              void* d_out, int out_size, void* d_ws, size_t ws_size,
                              hipStream_t stream)
{
    const float* x   = (const float*)d_in[0];
    const int*   src = (const int*)  d_in[1];
    const float* W1  = (const float*)d_in[2];
    const float* b1  = (const float*)d_in[3];
    const float* g1  = (const float*)d_in[4];
    const float* be1 = (const float*)d_in[5];
    const float* m1  = (const float*)d_in[6];
    const float* v1  = (const float*)d_in[7];
    const float* Wmr = (const float*)d_in[8];
    const float* bmr = (const float*)d_in[9];
    const float* W2  = (const float*)d_in[10];
    const float* b2  = (const float*)d_in[11];
    const float* g2  = (const float*)d_in[12];
    const float* be2 = (const float*)d_in[13];
    const float* m2  = (const float*)d_in[14];
    const float* v2  = (const float*)d_in[15];
    float* out = (float*)d_out;

    ushort* xn = (ushort*)d_ws;   // [NODES][128] bf16

    fc1_mfma<<<NODES / 64, 512, 0, stream>>>(x, W1, b1, g1, be1, m1, v1, xn);
    mrfc2_mfma<<<NODES / 64, 512, 0, stream>>>(xn, src, Wmr, bmr, W2, x,
                                               b2, g2, be2, m2, v2, out);
}

// Round 11
// 36.076 us; speedup vs baseline: 1.2776x; 1.2776x over previous
//
#include <hip/hip_runtime.h>

// Grapher block (DeepGCN MRConv) on MI355X — bf16 MFMA, 2 kernels.
// fc1 (coalesced+XOR-swizzled LDS transpose; W1 cvt on-the-fly; side-job
// converts Wmr/W2 -> bf16 scratch) -> fused mr+fc2 (bf16 weights, round-6 body).
// Scratch (d_ws): Wmrbf(128K) W2bf(64K), xn bf16 [32768][128] (8MB).
//
// MFMA 16x16x32 bf16 layout (guide §3, m89-verified):
//   A: row = lane&15, k = (lane>>4)*8 + j   (bf16x8 contiguous in k)
//   B: col = lane&15, k = (lane>>4)*8 + j
//   D: col = lane&15, row = (lane>>4)*4 + r
//
// NOTES from this session:
//  - rounds 7-9: cooperative fc1+mr fusion races — regular xn stores dirty in
//    producer-XCD L2 are NOT published by agent-scope __threadfence+grid.sync
//    on gfx950; the kernel boundary is the reliable publish point. 2 kernels.
//  - round 10: weight cvt inside the mrfc2 hot loop = −6.6 µs regression
//    (VALU repack in K-loop, m80 failure mode). Convert OUTSIDE hot loops.

typedef short bf8_t __attribute__((ext_vector_type(8)));
typedef float f4_t  __attribute__((ext_vector_type(4)));

namespace {
constexpr int Bn = 8, Cc = 128, Nn = 4096, Kk = 16, C2 = 256;
constexpr int NODES = Bn * Nn;
constexpr float EPSf = 1e-5f;
}

__device__ __forceinline__ unsigned short f2bf(float f) {
    unsigned u = __float_as_uint(f);
    u += 0x7fffu + ((u >> 16) & 1u);   // RNE
    return (unsigned short)(u >> 16);
}
__device__ __forceinline__ unsigned pk2(float a, float b) {
    return (unsigned)f2bf(a) | ((unsigned)f2bf(b) << 16);
}
__device__ __forceinline__ float bflo(unsigned u) { return __uint_as_float(u << 16); }
__device__ __forceinline__ float bfhi(unsigned u) { return __uint_as_float(u & 0xffff0000u); }
__device__ __forceinline__ unsigned diff2(unsigned o, unsigned m) {
    return pk2(bflo(o) - bflo(m), bfhi(o) - bfhi(m));
}

// load 8 consecutive fp32 weights -> one bf16x8 MFMA fragment (fc1 only)
__device__ __forceinline__ bf8_t cvt_frag(const float* __restrict__ p) {
    const float4 a = *(const float4*)(p);
    const float4 b = *(const float4*)(p + 4);
    union { uint4 u; bf8_t f; } r;
    r.u.x = pk2(a.x, a.y);
    r.u.y = pk2(a.z, a.w);
    r.u.z = pk2(b.x, b.y);
    r.u.w = pk2(b.z, b.w);
    return r.f;
}

// packed u16 min: valid as bf16-min because all values are >= 0 (post-ReLU)
#define PKMIN(a, b) asm("v_pk_min_u16 %0, %0, %1" : "+v"(a) : "v"(b))

// ---------------------------------------------------------------------------
// fc1: xn[n][o] = relu( BN( sum_c W1[o][c]*x[b][c][n] ) )
// block: 512 thr = 8 waves, tile 64 nodes x 128 o; wave w -> o-band 16w.
// Side-job (blocks 0..95): convert Wmr(65536)+W2(32768) fp32->bf16 scratch,
// 2 elems/thread, before staging (overlaps). Published at kernel boundary.
// ---------------------------------------------------------------------------
__global__ __launch_bounds__(512) void fc1_mfma(
    const float* __restrict__ x, const float* __restrict__ W1,
    const float* __restrict__ b1, const float* __restrict__ g1,
    const float* __restrict__ be1, const float* __restrict__ m1,
    const float* __restrict__ v1, const float* __restrict__ Wmr,
    const float* __restrict__ W2, ushort* __restrict__ Wmrbf,
    ushort* __restrict__ W2bf, ushort* __restrict__ xn)
{
    __shared__ __align__(16) ushort xS[64 * 136];   // 17.4 KB
    __shared__ float scS[Cc], shS[Cc];
    const int t = threadIdx.x;
    const int bid = blockIdx.x;

    // side-job: weight conversion for the mrfc2 kernel (hot-loop-free)
    if (bid < 96) {
        const int e = bid * 1024 + t * 2;            // 96*512*2 = 98304 elems
        if (e < 65536) {
            const float2 v = *(const float2*)(Wmr + e);
            *(unsigned*)(Wmrbf + e) = pk2(v.x, v.y);
        } else {
            const float2 v = *(const float2*)(W2 + (e - 65536));
            *(unsigned*)(W2bf + (e - 65536)) = pk2(v.x, v.y);
        }
    }

    const int lb = (bid & 7) * 64 + (bid >> 3);     // XCD-local batch mapping
    const int node0 = lb * 64;
    const int b  = node0 >> 12;
    const int n0 = node0 & 4095;

    if (t < Cc) {
        const float s = g1[t] * rsqrtf(v1[t] + EPSf);
        scS[t] = s;
        shS[t] = (b1[t] - m1[t]) * s + be1[t];
    }

    // stage: thread = channels (2cp, 2cp+1) x 8 consecutive n (coalesced)
    {
        const int cp = t >> 3, q = t & 7;            // n = q*8 .. q*8+7
        const float* p0 = x + ((size_t)(b * Cc + 2 * cp)) * Nn + n0 + q * 8;
        const float* p1 = p0 + Nn;
        const float4 a0 = *(const float4*)(p0);
        const float4 a1 = *(const float4*)(p0 + 4);
        const float4 c0 = *(const float4*)(p1);
        const float4 c1 = *(const float4*)(p1 + 4);
        ushort* base = xS + (size_t)q * 8 * 136 + ((cp * 2) ^ (q << 3));
        *(unsigned*)(base + 0 * 136) = pk2(a0.x, c0.x);
        *(unsigned*)(base + 1 * 136) = pk2(a0.y, c0.y);
        *(unsigned*)(base + 2 * 136) = pk2(a0.z, c0.z);
        *(unsigned*)(base + 3 * 136) = pk2(a0.w, c0.w);
        *(unsigned*)(base + 4 * 136) = pk2(a1.x, c1.x);
        *(unsigned*)(base + 5 * 136) = pk2(a1.y, c1.y);
        *(unsigned*)(base + 6 * 136) = pk2(a1.z, c1.z);
        *(unsigned*)(base + 7 * 136) = pk2(a1.w, c1.w);
    }
    __syncthreads();

    const int w = t >> 6, lane = t & 63;
    const int row16 = lane & 15, kg = lane >> 4;

    f4_t acc[4];  // [nsub]
    const f4_t zero = {0.f, 0.f, 0.f, 0.f};
    #pragma unroll
    for (int j = 0; j < 4; ++j) acc[j] = zero;

    #pragma unroll
    for (int ks = 0; ks < 4; ++ks) {
        const int k0 = ks * 32 + kg * 8;
        const bf8_t aw = cvt_frag(W1 + (size_t)(w * 16 + row16) * Cc + k0);
        #pragma unroll
        for (int nsub = 0; nsub < 4; ++nsub) {
            const int n = nsub * 16 + row16;
            const bf8_t bx = *(const bf8_t*)(xS + n * 136 + (k0 ^ ((n >> 3) << 3)));
            acc[nsub] = __builtin_amdgcn_mfma_f32_16x16x32_bf16(aw, bx, acc[nsub], 0, 0, 0);
        }
    }

    // epilogue: lane owns o = o4..o4+3 (consecutive) for 4 node rows -> uint2
    const int o4 = w * 16 + kg * 4;
    const float s0 = scS[o4 + 0], s1 = scS[o4 + 1], s2 = scS[o4 + 2], s3 = scS[o4 + 3];
    const float h0 = shS[o4 + 0], h1 = shS[o4 + 1], h2 = shS[o4 + 2], h3 = shS[o4 + 3];
    #pragma unroll
    for (int nsub = 0; nsub < 4; ++nsub) {
        const int node = node0 + nsub * 16 + row16;
        float v0 = acc[nsub][0] * s0 + h0;
        float v1 = acc[nsub][1] * s1 + h1;
        float v2 = acc[nsub][2] * s2 + h2;
        float v3 = acc[nsub][3] * s3 + h3;
        v0 = v0 > 0.f ? v0 : 0.f;
        v1 = v1 > 0.f ? v1 : 0.f;
        v2 = v2 > 0.f ? v2 : 0.f;
        v3 = v3 > 0.f ? v3 : 0.f;
        uint2 pk;
        pk.x = pk2(v0, v1);
        pk.y = pk2(v2, v3);
        *(uint2*)(xn + (size_t)node * Cc + o4) = pk;
    }
}

// ---------------------------------------------------------------------------
// fused mr+fc2 per 64-node tile, 512 thr = 8 waves (round-6 body, bf16 W):
//   P1: cat = [xn | xn - min_k xn[src]]  -> catS (8 thr/node, 16-ch slices)
//   P2: hn  = relu(Wmr @ cat^T + bmr)    wave j-band 32; packed writeback->catS
//   P3: out = relu( BN(W2 @ hn^T) + x )  wave o-band 16
// XCD swizzle: bid%8 -> batch, so gathers hit XCD-local L2.
// ---------------------------------------------------------------------------
__global__ __launch_bounds__(512) void mrfc2_mfma(
    const ushort* __restrict__ xn, const int* __restrict__ src,
    const ushort* __restrict__ Wmrbf, const float* __restrict__ bmr,
    const ushort* __restrict__ W2bf, const float* __restrict__ x,
    const float* __restrict__ b2, const float* __restrict__ g2,
    const float* __restrict__ be2, const float* __restrict__ m2,
    const float* __restrict__ v2, float* __restrict__ out)
{
    __shared__ __align__(16) ushort catS[64 * 264];  // [node][256] pad->264
    __shared__ int srcS[64 * Kk];
    __shared__ float scS[Cc], shS[Cc];
    const int t = threadIdx.x;
    const int bid = blockIdx.x;
    const int lb = (bid & 7) * 64 + (bid >> 3);      // XCD-local batch mapping
    const int node0 = lb * 64;
    const int b  = node0 >> 12;
    const int n0 = node0 & 4095;

    if (t < Cc) {
        const float s = g2[t] * rsqrtf(v2[t] + EPSf);
        scS[t] = s;
        shS[t] = (b2[t] - m2[t]) * s + be2[t];
    }
    if (t < 256)
        ((int4*)srcS)[t] = ((const int4*)(src + (size_t)node0 * Kk))[t];
    __syncthreads();

    {   // P1: gather + u16-min + diff; 8 threads/node, 16 channels each
        const int nl = t >> 3, q = t & 7;
        const ushort* orow = xn + (size_t)(node0 + nl) * Cc + q * 16;
        uint4 ow0 = *(const uint4*)(orow + 0);
        uint4 ow1 = *(const uint4*)(orow + 8);
        const int* sl = srcS + nl * Kk;
        const ushort* sr = xn + (size_t)sl[0] * Cc + q * 16;
        uint4 mn0 = *(const uint4*)(sr + 0);
        uint4 mn1 = *(const uint4*)(sr + 8);
        #pragma unroll
        for (int k = 1; k < Kk; ++k) {
            const ushort* s = xn + (size_t)sl[k] * Cc + q * 16;
            uint4 v0 = *(const uint4*)(s + 0);
            uint4 v1 = *(const uint4*)(s + 8);
            PKMIN(mn0.x, v0.x); PKMIN(mn0.y, v0.y); PKMIN(mn0.z, v0.z); PKMIN(mn0.w, v0.w);
            PKMIN(mn1.x, v1.x); PKMIN(mn1.y, v1.y); PKMIN(mn1.z, v1.z); PKMIN(mn1.w, v1.w);
        }
        unsigned* crow = (unsigned*)(catS + nl * 264);
        *(uint4*)(crow + q * 8 + 0) = ow0;
        *(uint4*)(crow + q * 8 + 4) = ow1;
        uint4 d0, d1;
        d0.x = diff2(ow0.x, mn0.x); d0.y = diff2(ow0.y, mn0.y);
        d0.z = diff2(ow0.z, mn0.z); d0.w = diff2(ow0.w, mn0.w);
        d1.x = diff2(ow1.x, mn1.x); d1.y = diff2(ow1.y, mn1.y);
        d1.z = diff2(ow1.z, mn1.z); d1.w = diff2(ow1.w, mn1.w);
        *(uint4*)(crow + 64 + q * 8 + 0) = d0;
        *(uint4*)(crow + 64 + q * 8 + 4) = d1;
    }
    __syncthreads();

    const int w = t >> 6, lane = t & 63;
    const int row16 = lane & 15, kg = lane >> 4;

    // ---- P2: hn j-band = relu(Wmr[jb:jb+32] @ cat^T + bmr)  (D: row=j)
    const int jb = w * 32;
    {
        f4_t acc[2][4];  // [jsub][nsub]
        const f4_t zero = {0.f, 0.f, 0.f, 0.f};
        #pragma unroll
        for (int i = 0; i < 2; ++i)
            #pragma unroll
            for (int j = 0; j < 4; ++j) acc[i][j] = zero;

        #pragma unroll
        for (int ks = 0; ks < 8; ++ks) {
            const int k0 = ks * 32 + kg * 8;
            bf8_t aw[2], bc[4];
            #pragma unroll
            for (int jsub = 0; jsub < 2; ++jsub)
                aw[jsub] = *(const bf8_t*)(Wmrbf + (size_t)(jb + jsub * 16 + row16) * C2 + k0);
            #pragma unroll
            for (int nsub = 0; nsub < 4; ++nsub)
                bc[nsub] = *(const bf8_t*)(catS + (nsub * 16 + row16) * 264 + k0);
            #pragma unroll
            for (int jsub = 0; jsub < 2; ++jsub)
                #pragma unroll
                for (int nsub = 0; nsub < 4; ++nsub)
                    acc[jsub][nsub] = __builtin_amdgcn_mfma_f32_16x16x32_bf16(
                        aw[jsub], bc[nsub], acc[jsub][nsub], 0, 0, 0);
        }
        __syncthreads();  // all P2 reads of catS complete

        // writeback hn into catS: lane's 4 acc rows are consecutive j -> uint2
        #pragma unroll
        for (int jsub = 0; jsub < 2; ++jsub) {
            const float4 bb = *(const float4*)(bmr + jb + jsub * 16 + kg * 4);
            #pragma unroll
            for (int nsub = 0; nsub < 4; ++nsub) {
                float v0 = acc[jsub][nsub][0] + bb.x;
                float v1 = acc[jsub][nsub][1] + bb.y;
                float v2_ = acc[jsub][nsub][2] + bb.z;
                float v3 = acc[jsub][nsub][3] + bb.w;
                v0 = v0 > 0.f ? v0 : 0.f;
                v1 = v1 > 0.f ? v1 : 0.f;
                v2_ = v2_ > 0.f ? v2_ : 0.f;
                v3 = v3 > 0.f ? v3 : 0.f;
                uint2 pk;
                pk.x = pk2(v0, v1);
                pk.y = pk2(v2_, v3);
                *(uint2*)(catS + (nsub * 16 + row16) * 264 + jb + jsub * 16 + kg * 4) = pk;
            }
        }
    }
    __syncthreads();

    // ---- P3: out o-band = relu(BN2(W2[ob:ob+16] @ hn^T) + x)  (D: row=o)
    {
        const int ob = w * 16;
        f4_t acc[4];  // [nsub]
        const f4_t zero = {0.f, 0.f, 0.f, 0.f};
        #pragma unroll
        for (int j = 0; j < 4; ++j) acc[j] = zero;

        #pragma unroll
        for (int ks = 0; ks < 8; ++ks) {
            const int k0 = ks * 32 + kg * 8;
            const bf8_t aw = *(const bf8_t*)(W2bf + (size_t)(ob + row16) * C2 + k0);
            #pragma unroll
            for (int nsub = 0; nsub < 4; ++nsub) {
                const bf8_t bh = *(const bf8_t*)(catS + (nsub * 16 + row16) * 264 + k0);
                acc[nsub] = __builtin_amdgcn_mfma_f32_16x16x32_bf16(aw, bh, acc[nsub], 0, 0, 0);
            }
        }

        #pragma unroll
        for (int r = 0; r < 4; ++r) {
            const int o = ob + kg * 4 + r;
            const float s = scS[o], sh = shS[o];
            const float* xr = x   + ((size_t)(b * Cc + o)) * Nn + n0;
            float*       op = out + ((size_t)(b * Cc + o)) * Nn + n0;
            #pragma unroll
            for (int nsub = 0; nsub < 4; ++nsub) {
                const int nn = nsub * 16 + row16;
                float v = acc[nsub][r] * s + sh + xr[nn];
                v = v > 0.f ? v : 0.f;
                op[nn] = v;
            }
        }
    }
}

// ---------------------------------------------------------------------------
extern "C" void kernel_launch(void* const* d_in, const int* in_sizes, int n_in,
                              void* d_out, int out_size, void* d_ws, size_t ws_size,
                              hipStream_t stream)
{
    const float* x   = (const float*)d_in[0];
    const int*   src = (const int*)  d_in[1];
    const float* W1  = (const float*)d_in[2];
    const float* b1  = (const float*)d_in[3];
    const float* g1  = (const float*)d_in[4];
    const float* be1 = (const float*)d_in[5];
    const float* m1  = (const float*)d_in[6];
    const float* v1  = (const float*)d_in[7];
    const float* Wmr = (const float*)d_in[8];
    const float* bmr = (const float*)d_in[9];
    const float* W2  = (const float*)d_in[10];
    const float* b2  = (const float*)d_in[11];
    const float* g2  = (const float*)d_in[12];
    const float* be2 = (const float*)d_in[13];
    const float* m2  = (const float*)d_in[14];
    const float* v2  = (const float*)d_in[15];
    float* out = (float*)d_out;

    ushort* Wmrbf = (ushort*)d_ws;            // 65536 bf16
    ushort* W2bf  = Wmrbf + 65536;            // 32768 bf16
    ushort* xn    = W2bf + 32768;             // [NODES][128] bf16

    fc1_mfma<<<NODES / 64, 512, 0, stream>>>(x, W1, b1, g1, be1, m1, v1,
                                             Wmr, W2, Wmrbf, W2bf, xn);
    mrfc2_mfma<<<NODES / 64, 512, 0, stream>>>(xn, src, Wmrbf, bmr, W2bf, x,
                                               b2, g2, be2, m2, v2, out);
}

// Round 12
// 35.568 us; speedup vs baseline: 1.2958x; 1.0143x over previous
//
#include <hip/hip_runtime.h>

// Grapher block (DeepGCN MRConv) on MI355X — bf16 MFMA, 2 kernels.
// fc1 (coalesced+XOR-swizzled LDS transpose; W1 cvt on-the-fly; side-job
// converts Wmr/W2 -> bf16 scratch) -> fused mr+fc2 (T14 async residual stage).
// Scratch (d_ws): Wmrbf(128K) W2bf(64K), xn bf16 [32768][128] (8MB).
//
// MFMA 16x16x32 bf16 layout (guide §3, m89-verified):
//   A: row = lane&15, k = (lane>>4)*8 + j   (bf16x8 contiguous in k)
//   B: col = lane&15, k = (lane>>4)*8 + j
//   D: col = lane&15, row = (lane>>4)*4 + r
//
// NOTES from this session:
//  - rounds 7-9: cooperative fc1+mr fusion races — regular xn stores dirty in
//    producer-XCD L2 are NOT published by agent-scope __threadfence+grid.sync
//    on gfx950; the kernel boundary is the reliable publish point. 2 kernels.
//  - round 10: weight cvt inside the mrfc2 hot loop = −6.6 µs regression
//    (VALU repack in K-loop, m80 failure mode). Convert OUTSIDE hot loops.
//  - round 12: T14 — early-issue P3's x-residual tile into LDS; drop srcS
//    staging barrier; defer BN2 consts. 3 barriers instead of 4+.

typedef short bf8_t __attribute__((ext_vector_type(8)));
typedef float f4_t  __attribute__((ext_vector_type(4)));

namespace {
constexpr int Bn = 8, Cc = 128, Nn = 4096, Kk = 16, C2 = 256;
constexpr int NODES = Bn * Nn;
constexpr float EPSf = 1e-5f;
}

__device__ __forceinline__ unsigned short f2bf(float f) {
    unsigned u = __float_as_uint(f);
    u += 0x7fffu + ((u >> 16) & 1u);   // RNE
    return (unsigned short)(u >> 16);
}
__device__ __forceinline__ unsigned pk2(float a, float b) {
    return (unsigned)f2bf(a) | ((unsigned)f2bf(b) << 16);
}
__device__ __forceinline__ float bflo(unsigned u) { return __uint_as_float(u << 16); }
__device__ __forceinline__ float bfhi(unsigned u) { return __uint_as_float(u & 0xffff0000u); }
__device__ __forceinline__ unsigned diff2(unsigned o, unsigned m) {
    return pk2(bflo(o) - bflo(m), bfhi(o) - bfhi(m));
}

// load 8 consecutive fp32 weights -> one bf16x8 MFMA fragment (fc1 only)
__device__ __forceinline__ bf8_t cvt_frag(const float* __restrict__ p) {
    const float4 a = *(const float4*)(p);
    const float4 b = *(const float4*)(p + 4);
    union { uint4 u; bf8_t f; } r;
    r.u.x = pk2(a.x, a.y);
    r.u.y = pk2(a.z, a.w);
    r.u.z = pk2(b.x, b.y);
    r.u.w = pk2(b.z, b.w);
    return r.f;
}

// packed u16 min: valid as bf16-min because all values are >= 0 (post-ReLU)
#define PKMIN(a, b) asm("v_pk_min_u16 %0, %0, %1" : "+v"(a) : "v"(b))

// ---------------------------------------------------------------------------
// fc1: xn[n][o] = relu( BN( sum_c W1[o][c]*x[b][c][n] ) )
// block: 512 thr = 8 waves, tile 64 nodes x 128 o; wave w -> o-band 16w.
// Side-job (blocks 0..95): convert Wmr(65536)+W2(32768) fp32->bf16 scratch.
// ---------------------------------------------------------------------------
__global__ __launch_bounds__(512) void fc1_mfma(
    const float* __restrict__ x, const float* __restrict__ W1,
    const float* __restrict__ b1, const float* __restrict__ g1,
    const float* __restrict__ be1, const float* __restrict__ m1,
    const float* __restrict__ v1, const float* __restrict__ Wmr,
    const float* __restrict__ W2, ushort* __restrict__ Wmrbf,
    ushort* __restrict__ W2bf, ushort* __restrict__ xn)
{
    __shared__ __align__(16) ushort xS[64 * 136];   // 17.4 KB
    __shared__ float scS[Cc], shS[Cc];
    const int t = threadIdx.x;
    const int bid = blockIdx.x;

    // side-job: weight conversion for the mrfc2 kernel (hot-loop-free)
    if (bid < 96) {
        const int e = bid * 1024 + t * 2;            // 96*512*2 = 98304 elems
        if (e < 65536) {
            const float2 v = *(const float2*)(Wmr + e);
            *(unsigned*)(Wmrbf + e) = pk2(v.x, v.y);
        } else {
            const float2 v = *(const float2*)(W2 + (e - 65536));
            *(unsigned*)(W2bf + (e - 65536)) = pk2(v.x, v.y);
        }
    }

    const int lb = (bid & 7) * 64 + (bid >> 3);     // XCD-local batch mapping
    const int node0 = lb * 64;
    const int b  = node0 >> 12;
    const int n0 = node0 & 4095;

    if (t < Cc) {
        const float s = g1[t] * rsqrtf(v1[t] + EPSf);
        scS[t] = s;
        shS[t] = (b1[t] - m1[t]) * s + be1[t];
    }

    // stage: thread = channels (2cp, 2cp+1) x 8 consecutive n (coalesced)
    {
        const int cp = t >> 3, q = t & 7;            // n = q*8 .. q*8+7
        const float* p0 = x + ((size_t)(b * Cc + 2 * cp)) * Nn + n0 + q * 8;
        const float* p1 = p0 + Nn;
        const float4 a0 = *(const float4*)(p0);
        const float4 a1 = *(const float4*)(p0 + 4);
        const float4 c0 = *(const float4*)(p1);
        const float4 c1 = *(const float4*)(p1 + 4);
        ushort* base = xS + (size_t)q * 8 * 136 + ((cp * 2) ^ (q << 3));
        *(unsigned*)(base + 0 * 136) = pk2(a0.x, c0.x);
        *(unsigned*)(base + 1 * 136) = pk2(a0.y, c0.y);
        *(unsigned*)(base + 2 * 136) = pk2(a0.z, c0.z);
        *(unsigned*)(base + 3 * 136) = pk2(a0.w, c0.w);
        *(unsigned*)(base + 4 * 136) = pk2(a1.x, c1.x);
        *(unsigned*)(base + 5 * 136) = pk2(a1.y, c1.y);
        *(unsigned*)(base + 6 * 136) = pk2(a1.z, c1.z);
        *(unsigned*)(base + 7 * 136) = pk2(a1.w, c1.w);
    }
    __syncthreads();

    const int w = t >> 6, lane = t & 63;
    const int row16 = lane & 15, kg = lane >> 4;

    f4_t acc[4];  // [nsub]
    const f4_t zero = {0.f, 0.f, 0.f, 0.f};
    #pragma unroll
    for (int j = 0; j < 4; ++j) acc[j] = zero;

    #pragma unroll
    for (int ks = 0; ks < 4; ++ks) {
        const int k0 = ks * 32 + kg * 8;
        const bf8_t aw = cvt_frag(W1 + (size_t)(w * 16 + row16) * Cc + k0);
        #pragma unroll
        for (int nsub = 0; nsub < 4; ++nsub) {
            const int n = nsub * 16 + row16;
            const bf8_t bx = *(const bf8_t*)(xS + n * 136 + (k0 ^ ((n >> 3) << 3)));
            acc[nsub] = __builtin_amdgcn_mfma_f32_16x16x32_bf16(aw, bx, acc[nsub], 0, 0, 0);
        }
    }

    // epilogue: lane owns o = o4..o4+3 (consecutive) for 4 node rows -> uint2
    const int o4 = w * 16 + kg * 4;
    const float s0 = scS[o4 + 0], s1 = scS[o4 + 1], s2 = scS[o4 + 2], s3 = scS[o4 + 3];
    const float h0 = shS[o4 + 0], h1 = shS[o4 + 1], h2 = shS[o4 + 2], h3 = shS[o4 + 3];
    #pragma unroll
    for (int nsub = 0; nsub < 4; ++nsub) {
        const int node = node0 + nsub * 16 + row16;
        float v0 = acc[nsub][0] * s0 + h0;
        float v1 = acc[nsub][1] * s1 + h1;
        float v2 = acc[nsub][2] * s2 + h2;
        float v3 = acc[nsub][3] * s3 + h3;
        v0 = v0 > 0.f ? v0 : 0.f;
        v1 = v1 > 0.f ? v1 : 0.f;
        v2 = v2 > 0.f ? v2 : 0.f;
        v3 = v3 > 0.f ? v3 : 0.f;
        uint2 pk;
        pk.x = pk2(v0, v1);
        pk.y = pk2(v2, v3);
        *(uint2*)(xn + (size_t)node * Cc + o4) = pk;
    }
}

// ---------------------------------------------------------------------------
// fused mr+fc2 per 64-node tile, 512 thr = 8 waves:
//   start: issue x-residual tile loads (4 x float4 / thr)  [T14 early issue]
//   P1: cat = [xn | xn - min_k xn[src]] -> catS (src read direct, no barrier)
//        then ds_write x-residual -> xresS
//   P2: hn  = relu(Wmr @ cat^T + bmr)   wave j-band 32; packed writeback->catS
//   P3: out = relu( BN(W2 @ hn^T) + xresS )  wave o-band 16 (LDS residual)
// 3 barriers. XCD swizzle: bid%8 -> batch, gathers hit XCD-local L2.
// ---------------------------------------------------------------------------
__global__ __launch_bounds__(512) void mrfc2_mfma(
    const ushort* __restrict__ xn, const int* __restrict__ src,
    const ushort* __restrict__ Wmrbf, const float* __restrict__ bmr,
    const ushort* __restrict__ W2bf, const float* __restrict__ x,
    const float* __restrict__ b2, const float* __restrict__ g2,
    const float* __restrict__ be2, const float* __restrict__ m2,
    const float* __restrict__ v2, float* __restrict__ out)
{
    __shared__ __align__(16) ushort catS[64 * 264];   // [node][256] pad->264
    __shared__ __align__(16) float xresS[128 * 64];   // residual tile [o][n], 32 KB
    __shared__ float scS[Cc], shS[Cc];
    const int t = threadIdx.x;
    const int bid = blockIdx.x;
    const int lb = (bid & 7) * 64 + (bid >> 3);      // XCD-local batch mapping
    const int node0 = lb * 64;
    const int b  = node0 >> 12;
    const int n0 = node0 & 4095;

    // ---- T14: issue the P3 residual loads FIRST (consumed after P2)
    const int xo = t >> 2, xseg = t & 3;             // o = xo, n-seg = xseg*16
    const float* xsrc = x + ((size_t)(b * Cc + xo)) * Nn + n0 + xseg * 16;
    const float4 xr0 = ((const float4*)xsrc)[0];
    const float4 xr1 = ((const float4*)xsrc)[1];
    const float4 xr2 = ((const float4*)xsrc)[2];
    const float4 xr3 = ((const float4*)xsrc)[3];

    {   // P1: gather + u16-min + diff; 8 threads/node, 16 channels each
        const int nl = t >> 3, q = t & 7;
        const int node = node0 + nl;
        const int4 si0 = *(const int4*)(src + (size_t)node * Kk + 0);
        const int4 si1 = *(const int4*)(src + (size_t)node * Kk + 4);
        const int4 si2 = *(const int4*)(src + (size_t)node * Kk + 8);
        const int4 si3 = *(const int4*)(src + (size_t)node * Kk + 12);
        const int sl[16] = {si0.x, si0.y, si0.z, si0.w,
                            si1.x, si1.y, si1.z, si1.w,
                            si2.x, si2.y, si2.z, si2.w,
                            si3.x, si3.y, si3.z, si3.w};
        const ushort* orow = xn + (size_t)node * Cc + q * 16;
        uint4 ow0 = *(const uint4*)(orow + 0);
        uint4 ow1 = *(const uint4*)(orow + 8);
        const ushort* sr = xn + (size_t)sl[0] * Cc + q * 16;
        uint4 mn0 = *(const uint4*)(sr + 0);
        uint4 mn1 = *(const uint4*)(sr + 8);
        #pragma unroll
        for (int k = 1; k < Kk; ++k) {
            const ushort* s = xn + (size_t)sl[k] * Cc + q * 16;
            uint4 v0 = *(const uint4*)(s + 0);
            uint4 v1 = *(const uint4*)(s + 8);
            PKMIN(mn0.x, v0.x); PKMIN(mn0.y, v0.y); PKMIN(mn0.z, v0.z); PKMIN(mn0.w, v0.w);
            PKMIN(mn1.x, v1.x); PKMIN(mn1.y, v1.y); PKMIN(mn1.z, v1.z); PKMIN(mn1.w, v1.w);
        }
        unsigned* crow = (unsigned*)(catS + nl * 264);
        *(uint4*)(crow + q * 8 + 0) = ow0;
        *(uint4*)(crow + q * 8 + 4) = ow1;
        uint4 d0, d1;
        d0.x = diff2(ow0.x, mn0.x); d0.y = diff2(ow0.y, mn0.y);
        d0.z = diff2(ow0.z, mn0.z); d0.w = diff2(ow0.w, mn0.w);
        d1.x = diff2(ow1.x, mn1.x); d1.y = diff2(ow1.y, mn1.y);
        d1.z = diff2(ow1.z, mn1.z); d1.w = diff2(ow1.w, mn1.w);
        *(uint4*)(crow + 64 + q * 8 + 0) = d0;
        *(uint4*)(crow + 64 + q * 8 + 4) = d1;
    }

    // park the residual tile in LDS (loads issued long ago)
    {
        float* xd = xresS + xo * 64 + xseg * 16;
        ((float4*)xd)[0] = xr0;
        ((float4*)xd)[1] = xr1;
        ((float4*)xd)[2] = xr2;
        ((float4*)xd)[3] = xr3;
    }
    __syncthreads();   // catS + xresS ready

    const int w = t >> 6, lane = t & 63;
    const int row16 = lane & 15, kg = lane >> 4;

    // ---- P2: hn j-band = relu(Wmr[jb:jb+32] @ cat^T + bmr)  (D: row=j)
    const int jb = w * 32;
    {
        f4_t acc[2][4];  // [jsub][nsub]
        const f4_t zero = {0.f, 0.f, 0.f, 0.f};
        #pragma unroll
        for (int i = 0; i < 2; ++i)
            #pragma unroll
            for (int j = 0; j < 4; ++j) acc[i][j] = zero;

        #pragma unroll
        for (int ks = 0; ks < 8; ++ks) {
            const int k0 = ks * 32 + kg * 8;
            bf8_t aw[2], bc[4];
            #pragma unroll
            for (int jsub = 0; jsub < 2; ++jsub)
                aw[jsub] = *(const bf8_t*)(Wmrbf + (size_t)(jb + jsub * 16 + row16) * C2 + k0);
            #pragma unroll
            for (int nsub = 0; nsub < 4; ++nsub)
                bc[nsub] = *(const bf8_t*)(catS + (nsub * 16 + row16) * 264 + k0);
            #pragma unroll
            for (int jsub = 0; jsub < 2; ++jsub)
                #pragma unroll
                for (int nsub = 0; nsub < 4; ++nsub)
                    acc[jsub][nsub] = __builtin_amdgcn_mfma_f32_16x16x32_bf16(
                        aw[jsub], bc[nsub], acc[jsub][nsub], 0, 0, 0);
        }

        // BN2 consts (needed only in P3; visible after next barrier)
        if (t < Cc) {
            const float s = g2[t] * rsqrtf(v2[t] + EPSf);
            scS[t] = s;
            shS[t] = (b2[t] - m2[t]) * s + be2[t];
        }
        __syncthreads();  // all P2 reads of catS complete (+ scS visible)

        // writeback hn into catS: lane's 4 acc rows are consecutive j -> uint2
        #pragma unroll
        for (int jsub = 0; jsub < 2; ++jsub) {
            const float4 bb = *(const float4*)(bmr + jb + jsub * 16 + kg * 4);
            #pragma unroll
            for (int nsub = 0; nsub < 4; ++nsub) {
                float v0 = acc[jsub][nsub][0] + bb.x;
                float v1 = acc[jsub][nsub][1] + bb.y;
                float v2_ = acc[jsub][nsub][2] + bb.z;
                float v3 = acc[jsub][nsub][3] + bb.w;
                v0 = v0 > 0.f ? v0 : 0.f;
                v1 = v1 > 0.f ? v1 : 0.f;
                v2_ = v2_ > 0.f ? v2_ : 0.f;
                v3 = v3 > 0.f ? v3 : 0.f;
                uint2 pk;
                pk.x = pk2(v0, v1);
                pk.y = pk2(v2_, v3);
                *(uint2*)(catS + (nsub * 16 + row16) * 264 + jb + jsub * 16 + kg * 4) = pk;
            }
        }
    }
    __syncthreads();

    // ---- P3: out o-band = relu(BN2(W2[ob:ob+16] @ hn^T) + xresS)  (D: row=o)
    {
        const int ob = w * 16;
        f4_t acc[4];  // [nsub]
        const f4_t zero = {0.f, 0.f, 0.f, 0.f};
        #pragma unroll
        for (int j = 0; j < 4; ++j) acc[j] = zero;

        #pragma unroll
        for (int ks = 0; ks < 8; ++ks) {
            const int k0 = ks * 32 + kg * 8;
            const bf8_t aw = *(const bf8_t*)(W2bf + (size_t)(ob + row16) * C2 + k0);
            #pragma unroll
            for (int nsub = 0; nsub < 4; ++nsub) {
                const bf8_t bh = *(const bf8_t*)(catS + (nsub * 16 + row16) * 264 + k0);
                acc[nsub] = __builtin_amdgcn_mfma_f32_16x16x32_bf16(aw, bh, acc[nsub], 0, 0, 0);
            }
        }

        #pragma unroll
        for (int r = 0; r < 4; ++r) {
            const int o = ob + kg * 4 + r;
            const float s = scS[o], sh = shS[o];
            const float* xl = xresS + o * 64;
            float*       op = out + ((size_t)(b * Cc + o)) * Nn + n0;
            #pragma unroll
            for (int nsub = 0; nsub < 4; ++nsub) {
                const int nn = nsub * 16 + row16;
                float v = acc[nsub][r] * s + sh + xl[nn];
                v = v > 0.f ? v : 0.f;
                op[nn] = v;
            }
        }
    }
}

// ---------------------------------------------------------------------------
extern "C" void kernel_launch(void* const* d_in, const int* in_sizes, int n_in,
                              void* d_out, int out_size, void* d_ws, size_t ws_size,
                              hipStream_t stream)
{
    const float* x   = (const float*)d_in[0];
    const int*   src = (const int*)  d_in[1];
    const float* W1  = (const float*)d_in[2];
    const float* b1  = (const float*)d_in[3];
    const float* g1  = (const float*)d_in[4];
    const float* be1 = (const float*)d_in[5];
    const float* m1  = (const float*)d_in[6];
    const float* v1  = (const float*)d_in[7];
    const float* Wmr = (const float*)d_in[8];
    const float* bmr = (const float*)d_in[9];
    const float* W2  = (const float*)d_in[10];
    const float* b2  = (const float*)d_in[11];
    const float* g2  = (const float*)d_in[12];
    const float* be2 = (const float*)d_in[13];
    const float* m2  = (const float*)d_in[14];
    const float* v2  = (const float*)d_in[15];
    float* out = (float*)d_out;

    ushort* Wmrbf = (ushort*)d_ws;            // 65536 bf16
    ushort* W2bf  = Wmrbf + 65536;            // 32768 bf16
    ushort* xn    = W2bf + 32768;             // [NODES][128] bf16

    fc1_mfma<<<NODES / 64, 512, 0, stream>>>(x, W1, b1, g1, be1, m1, v1,
                                             Wmr, W2, Wmrbf, W2bf, xn);
    mrfc2_mfma<<<NODES / 64, 512, 0, stream>>>(xn, src, Wmrbf, bmr, W2bf, x,
                                               b2, g2, be2, m2, v2, out);
}